// Round 7
// baseline (153.100 us; speedup 1.0000x reference)
//
#include <hip/hip_runtime.h>
#include <stdint.h>

#define BI 128
#define BT 128
#define RR 36
#define WW 50
#define DD 1024
#define NN 6400       /* fg row stride, static */
#define SEPS 1e-6f
#define L2E20 28.853900817779268f   /* 20/ln2 */

typedef __attribute__((ext_vector_type(8))) short short8v;
typedef __attribute__((ext_vector_type(4))) float float4v;
typedef __attribute__((ext_vector_type(2))) unsigned int uint2v;

__device__ __forceinline__ unsigned short f2bf(float f){
  unsigned u = __float_as_uint(f);
  return (unsigned short)((u + 0x7FFFu + ((u >> 16) & 1u)) >> 16);
}

// ---- exclusive prefix scan of il (128) and cl (128); dst[128] = total ----
__global__ __launch_bounds__(256) void prefix_kernel(
    const int* __restrict__ il, const int* __restrict__ cl,
    int* __restrict__ rowoff, int* __restrict__ coloff){
  __shared__ int buf[2][128];
  const int t = threadIdx.x;
  const int which = t >> 7, j = t & 127;
  const int v = which ? cl[j] : il[j];
  buf[which][j] = v;
  __syncthreads();
  #pragma unroll
  for (int off = 1; off < 128; off <<= 1){
    int x = (j >= off) ? buf[which][j - off] : 0;
    __syncthreads();
    buf[which][j] += x;
    __syncthreads();
  }
  int* dst = which ? coloff : rowoff;
  dst[j] = buf[which][j] - v;                 // exclusive
  if (j == 127) dst[128] = buf[which][127];   // total (M' / N')
}

// ---- gather valid rows + f32->bf16 convert. Block = one source row. ----
__global__ __launch_bounds__(256) void gather_cvt_kernel(
    const float* __restrict__ imgs, const float* __restrict__ caps,
    const int* __restrict__ il, const int* __restrict__ cl,
    const int* __restrict__ rowoff, const int* __restrict__ coloff,
    unsigned short* __restrict__ Ab, unsigned short* __restrict__ Bb){
  const int b = blockIdx.x;
  const int t = threadIdx.x;
  if (b < BI * RR){
    const int i = b / RR, r = b % RR;
    if (r >= il[i]) return;
    const float4 v = *(const float4*)(imgs + (size_t)b * DD + t * 4);
    ushort4 o = make_ushort4(f2bf(v.x), f2bf(v.y), f2bf(v.z), f2bf(v.w));
    *(ushort4*)(Ab + (size_t)(rowoff[i] + r) * DD + t * 4) = o;
  } else {
    const int bb = b - BI * RR;
    const int c = bb / WW, w = bb % WW;
    if (w >= cl[c]) return;
    const float4 v = *(const float4*)(caps + (size_t)bb * DD + t * 4);
    ushort4 o = make_ushort4(f2bf(v.x), f2bf(v.y), f2bf(v.z), f2bf(v.w));
    *(ushort4*)(Bb + (size_t)(coloff[c] + w) * DD + t * 4) = o;
  }
}

// ---- m97-structure 128x128x64 GEMM over compacted rows; early-exit tiles ----
__global__ __launch_bounds__(256) void gemm_kernel(
    const unsigned short* __restrict__ A, const unsigned short* __restrict__ B,
    const int* __restrict__ rowoff, const int* __restrict__ coloff,
    float* __restrict__ C){
  __shared__ __align__(16) unsigned char LDS[32768];
  const int bx = blockIdx.x;
  const int swz = (bx & 7) * 225 + (bx >> 3);     // 1800 = 8*225, bijective
  const int mb = swz / 50, nb = swz % 50;
  const int m0 = mb * 128, n0 = nb * 128;
  const int Mp = rowoff[BI];                      // M' (runtime)
  const int Np = coloff[BT];                      // N'
  if (m0 >= Mp || n0 >= Np) return;               // uniform early-exit

  const int tid = threadIdx.x;
  const int lane = tid & 63, wv = tid >> 6;
  const int l15 = lane & 15, lhi = lane >> 4;
  const int wr = wv >> 1, wc = wv & 1;            // 2x2 wave grid, 64x64/wave

  const unsigned short* sA[4];
  const unsigned short* sB[4];
  #pragma unroll
  for (int j = 0; j < 4; j++){
    int u = j * 256 + tid;                        // 16B unit 0..1023
    int row = u >> 3;
    int kg = (u & 7) ^ (row & 7);                 // source pre-swizzle
    sA[j] = A + (size_t)(m0 + row) * DD + kg * 8;
    sB[j] = B + (size_t)(n0 + row) * DD + kg * 8;
  }

  float4v acc[4][4];
  #pragma unroll
  for (int a1 = 0; a1 < 4; a1++)
    #pragma unroll
    for (int b1 = 0; b1 < 4; b1++)
      acc[a1][b1] = (float4v){0.f, 0.f, 0.f, 0.f};

  for (int ch = 0; ch < 16; ch++){
    __syncthreads();
    #pragma unroll
    for (int j = 0; j < 4; j++){
      __builtin_amdgcn_global_load_lds(
          (const __attribute__((address_space(1))) void*)(sA[j] + ch * 64),
          (__attribute__((address_space(3))) void*)(LDS + (j * 256 + tid) * 16),
          16, 0, 0);
      __builtin_amdgcn_global_load_lds(
          (const __attribute__((address_space(1))) void*)(sB[j] + ch * 64),
          (__attribute__((address_space(3))) void*)(LDS + 16384 + (j * 256 + tid) * 16),
          16, 0, 0);
    }
    __syncthreads();
    #pragma unroll
    for (int s = 0; s < 2; s++){
      int kb = s * 4 + lhi;
      short8v af[4], bf[4];
      #pragma unroll
      for (int tr = 0; tr < 4; tr++){
        int row = wr * 64 + tr * 16 + l15;
        af[tr] = *(const short8v*)(LDS + (row * 8 + (kb ^ (row & 7))) * 16);
      }
      #pragma unroll
      for (int tw = 0; tw < 4; tw++){
        int row = wc * 64 + tw * 16 + l15;
        bf[tw] = *(const short8v*)(LDS + 16384 + (row * 8 + (kb ^ (row & 7))) * 16);
      }
      #pragma unroll
      for (int tr = 0; tr < 4; tr++)
        #pragma unroll
        for (int tw = 0; tw < 4; tw++)
          acc[tr][tw] = __builtin_amdgcn_mfma_f32_16x16x32_bf16(
              af[tr], bf[tw], acc[tr][tw], 0, 0, 0);
    }
  }

  // C/D layout: col = lane&15, row = lhi*4 + j (m89/m91, validated R1-R6)
  #pragma unroll
  for (int tr = 0; tr < 4; tr++)
    #pragma unroll
    for (int tw = 0; tw < 4; tw++)
      #pragma unroll
      for (int j = 0; j < 4; j++){
        int m = m0 + wr * 64 + tr * 16 + lhi * 4 + j;
        int n = n0 + wc * 64 + tw * 16 + l15;
        C[(size_t)m * NN + n] = acc[tr][tw][j];
      }
}

// ---- within-32 all-sum: 4 DPP row_ror adds + permlane16_swap (validated R6) ----
template<int CTRL>
__device__ __forceinline__ float dpp_add(float x){
  int y = __builtin_amdgcn_mov_dpp(__float_as_int(x), CTRL, 0xF, 0xF, true);
  return x + __int_as_float(y);
}
__device__ __forceinline__ float half32AllSum(float x){
  x = dpp_add<0x121>(x);   // row_ror:1
  x = dpp_add<0x122>(x);   // row_ror:2
  x = dpp_add<0x124>(x);   // row_ror:4
  x = dpp_add<0x128>(x);   // row_ror:8  -> per-16-group sums
  unsigned xi = __float_as_uint(x);
  uint2v r = __builtin_amdgcn_permlane16_swap(xi, xi, false, false);
  return __uint_as_float(r[0]) + __uint_as_float(r[1]);  // 32-half sum
}

// ---- X-macro row lists: 4 chunks of 9 rows (ilen>=10 -> chunks 0,1 always) ----
#define RL0(X) X(0) X(1) X(2) X(3) X(4) X(5) X(6) X(7) X(8)
#define RL1(X) X(9) X(10) X(11) X(12) X(13) X(14) X(15) X(16) X(17)
#define RL2(X) X(18) X(19) X(20) X(21) X(22) X(23) X(24) X(25) X(26)
#define RL3(X) X(27) X(28) X(29) X(30) X(31) X(32) X(33) X(34) X(35)
#define RL_ALL(X) RL0(X) RL1(X) RL2(X) RL3(X)

#define DECLP(r) float p0_##r = 0.0f, p1_##r = 0.0f;
#define INITP(r) { \
    const float a0 = v0 ? base[r * NN] : 0.0f; \
    const float a1 = v1 ? base[r * NN + 32] : 0.0f; \
    if (r < ilen){ \
      p0_##r = v0 ? exp2f(fmaf(a0, L2E20, -L2E20)) : 0.0f; \
      p1_##r = v1 ? exp2f(fmaf(a1, L2E20, -L2E20)) : 0.0f; \
      ts += p0_##r + p1_##r; } }
#define SCALEP(r) { p0_##r *= sc; p1_##r *= sc; }
#define ROWP(r) { \
    const float t_##r = half32AllSum(p0_##r + p1_##r); \
    const float rs_##r = __fdividef(inv_il, t_##r + SEPS); \
    p0_##r *= rs_##r; p1_##r *= rs_##r; }
#define COLP(r) { u0 += p0_##r; u1 += p1_##r; }
#define CSCP(r) { p0_##r *= cs0; p1_##r *= cs1; }
#define FINP(r) { \
    sim = fmaf(base[r * NN], p0_##r, sim); \
    sim = fmaf(base[r * NN + 32], p1_##r, sim); }

// ---- Sinkhorn: 2 pairs per wave, 72 named-scalar P values (no arrays ->
// no scratch alloca; R6's VGPR_Count=52 showed arrays were spilled).
// waves_per_eu(1,4): occupancy target <=4 waves/SIMD -> 128-VGPR budget. ----
__global__ __launch_bounds__(256)
__attribute__((amdgpu_waves_per_eu(1, 4)))
void sink_kernel(
    const float* __restrict__ fg, const int* __restrict__ il,
    const int* __restrict__ cl, const int* __restrict__ rowoff,
    const int* __restrict__ coloff, float* __restrict__ out){
  const int lane = threadIdx.x & 63;
  const int gw = blockIdx.x * 4 + (threadIdx.x >> 6);   // 8192 waves
  const int i = gw >> 6;                                // img
  const int j = gw & 63;                                // caption pair
  const int h = lane >> 5, hl = lane & 31;
  const int c = 2 * j + h;                              // this half's caption

  const int ilen = __builtin_amdgcn_readfirstlane(il[i]);
  const int ro   = __builtin_amdgcn_readfirstlane(rowoff[i]);
  const int clen = cl[c];                               // per-lane (per half)
  const int co   = coloff[c];                           // per-lane
  const float* base = fg + (size_t)ro * NN + co + hl;   // col0 addr; col1 = +32
  const float inv_il = __fdividef(1.0f, (float)ilen);
  const float inv_cl = __fdividef(1.0f, (float)clen);
  const bool v0 = (hl < clen);
  const bool v1 = (hl + 32 < clen);
  const bool g2 = (ilen > 18);                          // wave-uniform
  const bool g3 = (ilen > 27);

  RL_ALL(DECLP)

  float ts = 0.f;
  RL0(INITP) RL1(INITP)
  if (g2){ RL2(INITP) }
  if (g3){ RL3(INITP) }

  ts = half32AllSum(ts);
  const float sc = __fdividef(1.0f, ts + SEPS);         // P /= (sum + EPS)
  RL0(SCALEP) RL1(SCALEP)
  if (g2){ RL2(SCALEP) }
  if (g3){ RL3(SCALEP) }

  for (int it = 0; it < 3; it++){
    // u = rowsum + EPS ; P *= (1/ilen)/u   (rows with p=0 stay 0)
    RL0(ROWP) RL1(ROWP)
    if (g2){ RL2(ROWP) }
    if (g3){ RL3(ROWP) }
    float u0 = 0.f, u1 = 0.f;                           // colsums (in-lane)
    RL0(COLP) RL1(COLP)
    if (g2){ RL2(COLP) }
    if (g3){ RL3(COLP) }
    const float cs0 = __fdividef(inv_cl, u0 + SEPS);
    const float cs1 = __fdividef(inv_cl, u1 + SEPS);
    RL0(CSCP) RL1(CSCP)
    if (g2){ RL2(CSCP) }
    if (g3){ RL3(CSCP) }
  }

  // final: reload f (L2-hot; unpredicated safe: p=0 kills garbage, and any
  // overrun stays inside the big fg allocation in ws — poison floats benign)
  float sim = 0.f;
  RL0(FINP) RL1(FINP)
  if (g2){ RL2(FINP) }
  if (g3){ RL3(FINP) }

  sim = half32AllSum(sim);
  if (hl == 0) out[i * BT + c] = sim;
}

extern "C" void kernel_launch(void* const* d_in, const int* in_sizes, int n_in,
                              void* d_out, int out_size, void* d_ws, size_t ws_size,
                              hipStream_t stream){
  const float* imgs = (const float*)d_in[0];
  const float* caps = (const float*)d_in[1];
  const int* il = (const int*)d_in[2];
  const int* cl = (const int*)d_in[3];
  float* out = (float*)d_out;

  unsigned short* Ab = (unsigned short*)d_ws;               // [4608][1024] bf16
  unsigned short* Bb = Ab + (size_t)BI * RR * DD;           // [6400][1024] bf16
  float* fg = (float*)(Bb + (size_t)BT * WW * DD);          // [4608][6400] f32
  int* rowoff = (int*)(fg + (size_t)BI * RR * NN);          // [129]
  int* coloff = rowoff + 129;                               // [129]

  prefix_kernel<<<1, 256, 0, stream>>>(il, cl, rowoff, coloff);
  gather_cvt_kernel<<<BI * RR + BT * WW, 256, 0, stream>>>(
      imgs, caps, il, cl, rowoff, coloff, Ab, Bb);
  gemm_kernel<<<36 * 50, 256, 0, stream>>>(Ab, Bb, rowoff, coloff, fg);
  sink_kernel<<<(BI * BT) / 8, 256, 0, stream>>>(fg, il, cl, rowoff, coloff, out);
}

// Round 8
// 124.799 us; speedup vs baseline: 1.2268x; 1.2268x over previous
//
#include <hip/hip_runtime.h>
#include <stdint.h>

#define BI 128
#define BT 128
#define RR 36
#define WW 50
#define DD 1024
#define NN 6400       /* fg row stride, static */
#define SEPS 1e-6f
#define L2E20 28.853900817779268f   /* 20/ln2 */

typedef __attribute__((ext_vector_type(8))) short short8v;
typedef __attribute__((ext_vector_type(4))) float float4v;
typedef __attribute__((ext_vector_type(2))) unsigned int uint2v;

__device__ __forceinline__ unsigned short f2bf(float f){
  unsigned u = __float_as_uint(f);
  return (unsigned short)((u + 0x7FFFu + ((u >> 16) & 1u)) >> 16);
}

// ---- exclusive prefix scan of il (128) and cl (128); dst[128] = total ----
__global__ __launch_bounds__(256) void prefix_kernel(
    const int* __restrict__ il, const int* __restrict__ cl,
    int* __restrict__ rowoff, int* __restrict__ coloff){
  __shared__ int buf[2][128];
  const int t = threadIdx.x;
  const int which = t >> 7, j = t & 127;
  const int v = which ? cl[j] : il[j];
  buf[which][j] = v;
  __syncthreads();
  #pragma unroll
  for (int off = 1; off < 128; off <<= 1){
    int x = (j >= off) ? buf[which][j - off] : 0;
    __syncthreads();
    buf[which][j] += x;
    __syncthreads();
  }
  int* dst = which ? coloff : rowoff;
  dst[j] = buf[which][j] - v;                 // exclusive
  if (j == 127) dst[128] = buf[which][127];   // total (M' / N')
}

// ---- gather valid rows + f32->bf16 convert. Block = one source row. ----
__global__ __launch_bounds__(256) void gather_cvt_kernel(
    const float* __restrict__ imgs, const float* __restrict__ caps,
    const int* __restrict__ il, const int* __restrict__ cl,
    const int* __restrict__ rowoff, const int* __restrict__ coloff,
    unsigned short* __restrict__ Ab, unsigned short* __restrict__ Bb){
  const int b = blockIdx.x;
  const int t = threadIdx.x;
  if (b < BI * RR){
    const int i = b / RR, r = b % RR;
    if (r >= il[i]) return;
    const float4 v = *(const float4*)(imgs + (size_t)b * DD + t * 4);
    ushort4 o = make_ushort4(f2bf(v.x), f2bf(v.y), f2bf(v.z), f2bf(v.w));
    *(ushort4*)(Ab + (size_t)(rowoff[i] + r) * DD + t * 4) = o;
  } else {
    const int bb = b - BI * RR;
    const int c = bb / WW, w = bb % WW;
    if (w >= cl[c]) return;
    const float4 v = *(const float4*)(caps + (size_t)bb * DD + t * 4);
    ushort4 o = make_ushort4(f2bf(v.x), f2bf(v.y), f2bf(v.z), f2bf(v.w));
    *(ushort4*)(Bb + (size_t)(coloff[c] + w) * DD + t * 4) = o;
  }
}

// ---- m97-structure 128x128x64 GEMM over compacted rows; early-exit tiles ----
__global__ __launch_bounds__(256) void gemm_kernel(
    const unsigned short* __restrict__ A, const unsigned short* __restrict__ B,
    const int* __restrict__ rowoff, const int* __restrict__ coloff,
    float* __restrict__ C){
  __shared__ __align__(16) unsigned char LDS[32768];
  const int bx = blockIdx.x;
  const int swz = (bx & 7) * 225 + (bx >> 3);     // 1800 = 8*225, bijective
  const int mb = swz / 50, nb = swz % 50;
  const int m0 = mb * 128, n0 = nb * 128;
  const int Mp = rowoff[BI];                      // M' (runtime)
  const int Np = coloff[BT];                      // N'
  if (m0 >= Mp || n0 >= Np) return;               // uniform early-exit

  const int tid = threadIdx.x;
  const int lane = tid & 63, wv = tid >> 6;
  const int l15 = lane & 15, lhi = lane >> 4;
  const int wr = wv >> 1, wc = wv & 1;            // 2x2 wave grid, 64x64/wave

  const unsigned short* sA[4];
  const unsigned short* sB[4];
  #pragma unroll
  for (int j = 0; j < 4; j++){
    int u = j * 256 + tid;                        // 16B unit 0..1023
    int row = u >> 3;
    int kg = (u & 7) ^ (row & 7);                 // source pre-swizzle
    sA[j] = A + (size_t)(m0 + row) * DD + kg * 8;
    sB[j] = B + (size_t)(n0 + row) * DD + kg * 8;
  }

  float4v acc[4][4];
  #pragma unroll
  for (int a1 = 0; a1 < 4; a1++)
    #pragma unroll
    for (int b1 = 0; b1 < 4; b1++)
      acc[a1][b1] = (float4v){0.f, 0.f, 0.f, 0.f};

  for (int ch = 0; ch < 16; ch++){
    __syncthreads();
    #pragma unroll
    for (int j = 0; j < 4; j++){
      __builtin_amdgcn_global_load_lds(
          (const __attribute__((address_space(1))) void*)(sA[j] + ch * 64),
          (__attribute__((address_space(3))) void*)(LDS + (j * 256 + tid) * 16),
          16, 0, 0);
      __builtin_amdgcn_global_load_lds(
          (const __attribute__((address_space(1))) void*)(sB[j] + ch * 64),
          (__attribute__((address_space(3))) void*)(LDS + 16384 + (j * 256 + tid) * 16),
          16, 0, 0);
    }
    __syncthreads();
    #pragma unroll
    for (int s = 0; s < 2; s++){
      int kb = s * 4 + lhi;
      short8v af[4], bf[4];
      #pragma unroll
      for (int tr = 0; tr < 4; tr++){
        int row = wr * 64 + tr * 16 + l15;
        af[tr] = *(const short8v*)(LDS + (row * 8 + (kb ^ (row & 7))) * 16);
      }
      #pragma unroll
      for (int tw = 0; tw < 4; tw++){
        int row = wc * 64 + tw * 16 + l15;
        bf[tw] = *(const short8v*)(LDS + 16384 + (row * 8 + (kb ^ (row & 7))) * 16);
      }
      #pragma unroll
      for (int tr = 0; tr < 4; tr++)
        #pragma unroll
        for (int tw = 0; tw < 4; tw++)
          acc[tr][tw] = __builtin_amdgcn_mfma_f32_16x16x32_bf16(
              af[tr], bf[tw], acc[tr][tw], 0, 0, 0);
    }
  }

  // C/D layout: col = lane&15, row = lhi*4 + j (m89/m91, validated R1-R7)
  #pragma unroll
  for (int tr = 0; tr < 4; tr++)
    #pragma unroll
    for (int tw = 0; tw < 4; tw++)
      #pragma unroll
      for (int j = 0; j < 4; j++){
        int m = m0 + wr * 64 + tr * 16 + lhi * 4 + j;
        int n = n0 + wc * 64 + tw * 16 + l15;
        C[(size_t)m * NN + n] = acc[tr][tw][j];
      }
}

// ---- reduction helpers (all validated in R1-R6 kernels) ----
template<int CTRL>
__device__ __forceinline__ float dpp_add(float x){
  int y = __builtin_amdgcn_mov_dpp(__float_as_int(x), CTRL, 0xF, 0xF, true);
  return x + __int_as_float(y);
}
// sum within each 16-lane group (4 fused DPP adds)
__device__ __forceinline__ float q16sum(float x){
  x = dpp_add<0x121>(x);   // row_ror:1
  x = dpp_add<0x122>(x);   // row_ror:2
  x = dpp_add<0x124>(x);   // row_ror:4
  x = dpp_add<0x128>(x);   // row_ror:8
  return x;
}
// combine adjacent 16-groups (within each 32-half)
__device__ __forceinline__ float pl16comb(float x){
  unsigned xi = __float_as_uint(x);
  uint2v r = __builtin_amdgcn_permlane16_swap(xi, xi, false, false);
  return __uint_as_float(r[0]) + __uint_as_float(r[1]);
}
// combine the two 32-halves
__device__ __forceinline__ float pl32comb(float x){
  unsigned xi = __float_as_uint(x);
  uint2v r = __builtin_amdgcn_permlane32_swap(xi, xi, false, false);
  return __uint_as_float(r[0]) + __uint_as_float(r[1]);
}

// ---- Sinkhorn: ONE pair per wave, 4-way row-split layout.
// Quarter q (lanes 16q..16q+15) owns rows 9q..9q+8; lane (q,t) holds
// columns t, t+16, t+32, t+48 of its 9 rows -> 36 named p-scalars/lane
// (fits the observed ~64-VGPR allocator budget; R6/R7 showed 72+ spills).
// Row reduce = within-16 (4 DPP adds), 9 rounds/iter, each serving 4 rows. ----
#define RL9(X) X(0) X(1) X(2) X(3) X(4) X(5) X(6) X(7) X(8)
#define DECLP(k) float p##k##0=0.f, p##k##1=0.f, p##k##2=0.f, p##k##3=0.f;
#define INITP(k) { \
    const int vo = off0 + k * NN; \
    const bool rv = (r0 + k) < ilen; \
    const float a0 = base[vo], a1 = base[vo + 16]; \
    const float a2 = base[vo + 32], a3 = base[vo + 48]; \
    p##k##0 = (rv && v0) ? exp2f(fmaf(a0, L2E20, -L2E20)) : 0.f; \
    p##k##1 = (rv && v1) ? exp2f(fmaf(a1, L2E20, -L2E20)) : 0.f; \
    p##k##2 = (rv && v2) ? exp2f(fmaf(a2, L2E20, -L2E20)) : 0.f; \
    p##k##3 = (rv && v3) ? exp2f(fmaf(a3, L2E20, -L2E20)) : 0.f; \
    ts += (p##k##0 + p##k##1) + (p##k##2 + p##k##3); }
#define SCAL0(k) { p##k##0 *= sc; p##k##1 *= sc; p##k##2 *= sc; p##k##3 *= sc; }
#define ROWP(k) { \
    float u = (p##k##0 + p##k##1) + (p##k##2 + p##k##3); \
    u = q16sum(u); \
    const float rs = __fdividef(inv_il, u + SEPS); \
    p##k##0 *= rs; p##k##1 *= rs; p##k##2 *= rs; p##k##3 *= rs; }
#define COLA(k) { s0 += p##k##0; s1 += p##k##1; s2 += p##k##2; s3 += p##k##3; }
#define CSC(k) { p##k##0 *= cs0; p##k##1 *= cs1; p##k##2 *= cs2; p##k##3 *= cs3; }
#define FINP(k) { \
    const int vo = off0 + k * NN; \
    sim = fmaf(base[vo],      p##k##0, sim); \
    sim = fmaf(base[vo + 16], p##k##1, sim); \
    sim = fmaf(base[vo + 32], p##k##2, sim); \
    sim = fmaf(base[vo + 48], p##k##3, sim); }

__global__ __launch_bounds__(256) void sink_kernel(
    const float* __restrict__ fg, const int* __restrict__ il,
    const int* __restrict__ cl, const int* __restrict__ rowoff,
    const int* __restrict__ coloff, float* __restrict__ out){
  const int lane = threadIdx.x & 63;
  const int gw = blockIdx.x * 4 + (threadIdx.x >> 6);   // 16384 waves
  const int i = gw >> 7, c = gw & 127;
  const int q = lane >> 4, t = lane & 15;

  const int ilen = __builtin_amdgcn_readfirstlane(il[i]);
  const int clen = __builtin_amdgcn_readfirstlane(cl[c]);
  const int ro   = __builtin_amdgcn_readfirstlane(rowoff[i]);
  const int co   = __builtin_amdgcn_readfirstlane(coloff[c]);
  const float* base = fg + (size_t)ro * NN + co;        // wave-uniform (saddr)
  const float inv_il = __fdividef(1.0f, (float)ilen);
  const float inv_cl = __fdividef(1.0f, (float)clen);
  const bool v0 = (t      < clen);
  const bool v1 = (t + 16 < clen);
  const bool v2 = (t + 32 < clen);
  const bool v3 = (t + 48 < clen);
  const int r0 = 9 * q;                                 // this quarter's rows
  const int off0 = r0 * NN + t;                         // 32-bit elem offset

  RL9(DECLP)

  // init: P = exp(-(1-fg)/lambda), masked; global sum over whole wave
  float ts = 0.f;
  RL9(INITP)
  ts = q16sum(ts);
  ts = pl16comb(ts);
  ts = pl32comb(ts);
  const float sc = __fdividef(1.0f, ts + SEPS);         // P /= (sum + EPS)
  RL9(SCAL0)

  for (int it = 0; it < 3; it++){
    // row pass: u = rowsum + EPS ; P *= (1/ilen)/u  (4 rows per round via SIMT)
    RL9(ROWP)
    // col pass: in-lane partials + 2 swap stages -> full 36-row colsum
    float s0 = 0.f, s1 = 0.f, s2 = 0.f, s3 = 0.f;
    RL9(COLA)
    s0 = pl16comb(s0); s0 = pl32comb(s0);
    s1 = pl16comb(s1); s1 = pl32comb(s1);
    s2 = pl16comb(s2); s2 = pl32comb(s2);
    s3 = pl16comb(s3); s3 = pl32comb(s3);
    const float cs0 = __fdividef(inv_cl, s0 + SEPS);
    const float cs1 = __fdividef(inv_cl, s1 + SEPS);
    const float cs2 = __fdividef(inv_cl, s2 + SEPS);
    const float cs3 = __fdividef(inv_cl, s3 + SEPS);
    RL9(CSC)
  }

  // final: sim = sum f*P (reload f, L2-hot; p=0 kills invalid/garbage entries)
  float sim = 0.f;
  RL9(FINP)
  sim = q16sum(sim);
  sim = pl16comb(sim);
  sim = pl32comb(sim);
  if (lane == 0) out[i * BT + c] = sim;
}

extern "C" void kernel_launch(void* const* d_in, const int* in_sizes, int n_in,
                              void* d_out, int out_size, void* d_ws, size_t ws_size,
                              hipStream_t stream){
  const float* imgs = (const float*)d_in[0];
  const float* caps = (const float*)d_in[1];
  const int* il = (const int*)d_in[2];
  const int* cl = (const int*)d_in[3];
  float* out = (float*)d_out;

  unsigned short* Ab = (unsigned short*)d_ws;               // [4608][1024] bf16
  unsigned short* Bb = Ab + (size_t)BI * RR * DD;           // [6400][1024] bf16
  float* fg = (float*)(Bb + (size_t)BT * WW * DD);          // [4608][6400] f32
  int* rowoff = (int*)(fg + (size_t)BI * RR * NN);          // [129]
  int* coloff = rowoff + 129;                               // [129]

  prefix_kernel<<<1, 256, 0, stream>>>(il, cl, rowoff, coloff);
  gather_cvt_kernel<<<BI * RR + BT * WW, 256, 0, stream>>>(
      imgs, caps, il, cl, rowoff, coloff, Ab, Bb);
  gemm_kernel<<<36 * 50, 256, 0, stream>>>(Ab, Bb, rowoff, coloff, fg);
  sink_kernel<<<(BI * BT) / 4, 256, 0, stream>>>(fg, il, cl, rowoff, coloff, out);
}

// Round 9
// 116.443 us; speedup vs baseline: 1.3148x; 1.0718x over previous
//
#include <hip/hip_runtime.h>
#include <stdint.h>

#define BI 128
#define BT 128
#define RR 36
#define WW 50
#define DD 1024
#define NN 6400       /* fg row stride, static */
#define SEPS 1e-6f
#define L2E20 28.853900817779268f   /* 20/ln2 */

typedef __attribute__((ext_vector_type(8))) short short8v;
typedef __attribute__((ext_vector_type(4))) float float4v;
typedef __attribute__((ext_vector_type(2))) unsigned int uint2v;

__device__ __forceinline__ unsigned short f2bf(float f){
  unsigned u = __float_as_uint(f);
  return (unsigned short)((u + 0x7FFFu + ((u >> 16) & 1u)) >> 16);
}

// ---- exclusive prefix scan of il (128) and cl (128); dst[128] = total ----
__global__ __launch_bounds__(256) void prefix_kernel(
    const int* __restrict__ il, const int* __restrict__ cl,
    int* __restrict__ rowoff, int* __restrict__ coloff){
  __shared__ int buf[2][128];
  const int t = threadIdx.x;
  const int which = t >> 7, j = t & 127;
  const int v = which ? cl[j] : il[j];
  buf[which][j] = v;
  __syncthreads();
  #pragma unroll
  for (int off = 1; off < 128; off <<= 1){
    int x = (j >= off) ? buf[which][j - off] : 0;
    __syncthreads();
    buf[which][j] += x;
    __syncthreads();
  }
  int* dst = which ? coloff : rowoff;
  dst[j] = buf[which][j] - v;                 // exclusive
  if (j == 127) dst[128] = buf[which][127];   // total (M' / N')
}

// ---- gather valid rows + f32->bf16 convert. Block = one source row. ----
__global__ __launch_bounds__(256) void gather_cvt_kernel(
    const float* __restrict__ imgs, const float* __restrict__ caps,
    const int* __restrict__ il, const int* __restrict__ cl,
    const int* __restrict__ rowoff, const int* __restrict__ coloff,
    unsigned short* __restrict__ Ab, unsigned short* __restrict__ Bb){
  const int b = blockIdx.x;
  const int t = threadIdx.x;
  if (b < BI * RR){
    const int i = b / RR, r = b % RR;
    if (r >= il[i]) return;
    const float4 v = *(const float4*)(imgs + (size_t)b * DD + t * 4);
    ushort4 o = make_ushort4(f2bf(v.x), f2bf(v.y), f2bf(v.z), f2bf(v.w));
    *(ushort4*)(Ab + (size_t)(rowoff[i] + r) * DD + t * 4) = o;
  } else {
    const int bb = b - BI * RR;
    const int c = bb / WW, w = bb % WW;
    if (w >= cl[c]) return;
    const float4 v = *(const float4*)(caps + (size_t)bb * DD + t * 4);
    ushort4 o = make_ushort4(f2bf(v.x), f2bf(v.y), f2bf(v.z), f2bf(v.w));
    *(ushort4*)(Bb + (size_t)(coloff[c] + w) * DD + t * 4) = o;
  }
}

// ---- 128x128 GEMM, BK=32, double-buffered LDS (2 x 16KB = same 32KB),
// T3 minimum 2-phase: STAGE(next) -> vmcnt(4) -> s_barrier -> compute(cur)
// -> s_barrier. Counted vmcnt never drains to 0 mid-loop.
// LDS layout per buffer: A = 512 units x 16B (8KB), B at +8192.
// Row-pair swizzle: unit(row,kg) = (row>>1)*8 + (((row&1)*4+kg) ^ ((row>>1)&7))
// -> each 8-lane group tiles all 32 banks exactly (2-way = free). Inverse
// pre-applied on the global source (both-sides-or-neither, rule #21). ----
__global__ __launch_bounds__(256) void gemm_kernel(
    const unsigned short* __restrict__ A, const unsigned short* __restrict__ B,
    const int* __restrict__ rowoff, const int* __restrict__ coloff,
    float* __restrict__ C){
  __shared__ __align__(16) unsigned char LDS[32768];
  const int bx = blockIdx.x;
  const int swz = (bx & 7) * 225 + (bx >> 3);     // 1800 = 8*225, bijective
  const int mb = swz / 50, nb = swz % 50;
  const int m0 = mb * 128, n0 = nb * 128;
  const int Mp = rowoff[BI];                      // M' (runtime)
  const int Np = coloff[BT];                      // N'
  if (m0 >= Mp || n0 >= Np) return;               // uniform early-exit

  const int tid = threadIdx.x;
  const int lane = tid & 63, wv = tid >> 6;
  const int l15 = lane & 15, lhi = lane >> 4;
  const int wr = wv >> 1, wc = wv & 1;            // 2x2 wave grid, 64x64/wave

  // staging sources: 4 units/thread/chunk (u = j*256+tid; A: u<512, B: u>=512)
  const unsigned short* sp[4];
  #pragma unroll
  for (int j = 0; j < 4; j++){
    const int u = j * 256 + tid;
    const int v = u & 511;
    const int sup = v >> 3, slot = v & 7;
    const int sub = slot ^ (sup & 7);             // inverse of store swizzle
    const int row = sup * 2 + (sub >> 2);
    const int kg  = sub & 3;
    sp[j] = ((u < 512) ? (A + (size_t)(m0 + row) * DD)
                       : (B + (size_t)(n0 + row) * DD)) + kg * 8;
  }

  float4v acc[4][4];
  #pragma unroll
  for (int a1 = 0; a1 < 4; a1++)
    #pragma unroll
    for (int b1 = 0; b1 < 4; b1++)
      acc[a1][b1] = (float4v){0.f, 0.f, 0.f, 0.f};

#define STAGE(BUF, CH) { \
    _Pragma("unroll") \
    for (int j = 0; j < 4; j++) \
      __builtin_amdgcn_global_load_lds( \
          (const __attribute__((address_space(1))) void*)(sp[j] + (CH) * 32), \
          (__attribute__((address_space(3))) void*)(LDS + (BUF) * 16384 + (j * 256 + tid) * 16), \
          16, 0, 0); }

#define LUNIT(row) (((row) >> 1) * 8 + (((((row) & 1) << 2) + lhi) ^ (((row) >> 1) & 7)))

#define COMPUTE(BUF) { \
    short8v af[4], bf[4]; \
    _Pragma("unroll") \
    for (int tr = 0; tr < 4; tr++){ \
      const int row = wr * 64 + tr * 16 + l15; \
      af[tr] = *(const short8v*)(LDS + (BUF) * 16384 + LUNIT(row) * 16); \
    } \
    _Pragma("unroll") \
    for (int tw = 0; tw < 4; tw++){ \
      const int row = wc * 64 + tw * 16 + l15; \
      bf[tw] = *(const short8v*)(LDS + (BUF) * 16384 + 8192 + LUNIT(row) * 16); \
    } \
    _Pragma("unroll") \
    for (int tr = 0; tr < 4; tr++) \
      _Pragma("unroll") \
      for (int tw = 0; tw < 4; tw++) \
        acc[tr][tw] = __builtin_amdgcn_mfma_f32_16x16x32_bf16( \
            af[tr], bf[tw], acc[tr][tw], 0, 0, 0); }

#define WAIT4  asm volatile("s_waitcnt vmcnt(4)" ::: "memory")
#define WAIT0  asm volatile("s_waitcnt vmcnt(0)" ::: "memory")
#define BAR    __builtin_amdgcn_s_barrier()

  STAGE(0, 0);                    // prologue
  #pragma unroll 1
  for (int ch = 0; ch < 30; ch += 2){
    STAGE(1, ch + 1);
    WAIT4; BAR;
    COMPUTE(0);                   // chunk ch
    BAR;
    STAGE(0, ch + 2);
    WAIT4; BAR;
    COMPUTE(1);                   // chunk ch+1
    BAR;
  }
  STAGE(1, 31);
  WAIT4; BAR;
  COMPUTE(0);                     // chunk 30
  WAIT0; BAR;
  COMPUTE(1);                     // chunk 31

#undef STAGE
#undef LUNIT
#undef COMPUTE
#undef WAIT4
#undef WAIT0
#undef BAR

  // C/D layout: col = lane&15, row = lhi*4 + j (m89/m91, validated R1-R8)
  #pragma unroll
  for (int tr = 0; tr < 4; tr++)
    #pragma unroll
    for (int tw = 0; tw < 4; tw++)
      #pragma unroll
      for (int j = 0; j < 4; j++){
        int m = m0 + wr * 64 + tr * 16 + lhi * 4 + j;
        int n = n0 + wc * 64 + tw * 16 + l15;
        C[(size_t)m * NN + n] = acc[tr][tw][j];
      }
}

// ---- reduction helpers (validated R1-R8) ----
template<int CTRL>
__device__ __forceinline__ float dpp_add(float x){
  int y = __builtin_amdgcn_mov_dpp(__float_as_int(x), CTRL, 0xF, 0xF, true);
  return x + __int_as_float(y);
}
__device__ __forceinline__ float q16sum(float x){
  x = dpp_add<0x121>(x);   // row_ror:1
  x = dpp_add<0x122>(x);   // row_ror:2
  x = dpp_add<0x124>(x);   // row_ror:4
  x = dpp_add<0x128>(x);   // row_ror:8
  return x;
}
__device__ __forceinline__ float pl16comb(float x){
  unsigned xi = __float_as_uint(x);
  uint2v r = __builtin_amdgcn_permlane16_swap(xi, xi, false, false);
  return __uint_as_float(r[0]) + __uint_as_float(r[1]);
}
__device__ __forceinline__ float pl32comb(float x){
  unsigned xi = __float_as_uint(x);
  uint2v r = __builtin_amdgcn_permlane32_swap(xi, xi, false, false);
  return __uint_as_float(r[0]) + __uint_as_float(r[1]);
}

// ---- Sinkhorn: ONE pair per wave, 4-way row-split (validated R8).
// Quarter q owns rows 9q..9q+8; lane (q,t) holds cols t,t+16,t+32,t+48. ----
#define RL9(X) X(0) X(1) X(2) X(3) X(4) X(5) X(6) X(7) X(8)
#define DECLP(k) float p##k##0=0.f, p##k##1=0.f, p##k##2=0.f, p##k##3=0.f;
#define INITP(k) { \
    const int vo = off0 + k * NN; \
    const bool rv = (r0 + k) < ilen; \
    const float a0 = base[vo], a1 = base[vo + 16]; \
    const float a2 = base[vo + 32], a3 = base[vo + 48]; \
    p##k##0 = (rv && v0) ? exp2f(fmaf(a0, L2E20, -L2E20)) : 0.f; \
    p##k##1 = (rv && v1) ? exp2f(fmaf(a1, L2E20, -L2E20)) : 0.f; \
    p##k##2 = (rv && v2) ? exp2f(fmaf(a2, L2E20, -L2E20)) : 0.f; \
    p##k##3 = (rv && v3) ? exp2f(fmaf(a3, L2E20, -L2E20)) : 0.f; \
    ts += (p##k##0 + p##k##1) + (p##k##2 + p##k##3); }
#define SCAL0(k) { p##k##0 *= sc; p##k##1 *= sc; p##k##2 *= sc; p##k##3 *= sc; }
#define ROWP(k) { \
    float u = (p##k##0 + p##k##1) + (p##k##2 + p##k##3); \
    u = q16sum(u); \
    const float rs = __fdividef(inv_il, u + SEPS); \
    p##k##0 *= rs; p##k##1 *= rs; p##k##2 *= rs; p##k##3 *= rs; }
#define COLA(k) { s0 += p##k##0; s1 += p##k##1; s2 += p##k##2; s3 += p##k##3; }
#define CSC(k) { p##k##0 *= cs0; p##k##1 *= cs1; p##k##2 *= cs2; p##k##3 *= cs3; }
#define FINP(k) { \
    const int vo = off0 + k * NN; \
    sim = fmaf(base[vo],      p##k##0, sim); \
    sim = fmaf(base[vo + 16], p##k##1, sim); \
    sim = fmaf(base[vo + 32], p##k##2, sim); \
    sim = fmaf(base[vo + 48], p##k##3, sim); }

__global__ __launch_bounds__(256) void sink_kernel(
    const float* __restrict__ fg, const int* __restrict__ il,
    const int* __restrict__ cl, const int* __restrict__ rowoff,
    const int* __restrict__ coloff, float* __restrict__ out){
  const int lane = threadIdx.x & 63;
  const int gw = blockIdx.x * 4 + (threadIdx.x >> 6);   // 16384 waves
  const int i = gw >> 7, c = gw & 127;
  const int q = lane >> 4, t = lane & 15;

  const int ilen = __builtin_amdgcn_readfirstlane(il[i]);
  const int clen = __builtin_amdgcn_readfirstlane(cl[c]);
  const int ro   = __builtin_amdgcn_readfirstlane(rowoff[i]);
  const int co   = __builtin_amdgcn_readfirstlane(coloff[c]);
  const float* base = fg + (size_t)ro * NN + co;        // wave-uniform (saddr)
  const float inv_il = __fdividef(1.0f, (float)ilen);
  const float inv_cl = __fdividef(1.0f, (float)clen);
  const bool v0 = (t      < clen);
  const bool v1 = (t + 16 < clen);
  const bool v2 = (t + 32 < clen);
  const bool v3 = (t + 48 < clen);
  const int r0 = 9 * q;                                 // this quarter's rows
  const int off0 = r0 * NN + t;                         // 32-bit elem offset

  RL9(DECLP)

  float ts = 0.f;
  RL9(INITP)
  ts = q16sum(ts);
  ts = pl16comb(ts);
  ts = pl32comb(ts);
  const float sc = __fdividef(1.0f, ts + SEPS);         // P /= (sum + EPS)
  RL9(SCAL0)

  for (int it = 0; it < 3; it++){
    RL9(ROWP)                                           // 9 rounds, 4 rows each
    float s0 = 0.f, s1 = 0.f, s2 = 0.f, s3 = 0.f;
    RL9(COLA)
    s0 = pl16comb(s0); s0 = pl32comb(s0);
    s1 = pl16comb(s1); s1 = pl32comb(s1);
    s2 = pl16comb(s2); s2 = pl32comb(s2);
    s3 = pl16comb(s3); s3 = pl32comb(s3);
    const float cs0 = __fdividef(inv_cl, s0 + SEPS);
    const float cs1 = __fdividef(inv_cl, s1 + SEPS);
    const float cs2 = __fdividef(inv_cl, s2 + SEPS);
    const float cs3 = __fdividef(inv_cl, s3 + SEPS);
    RL9(CSC)
  }

  float sim = 0.f;
  RL9(FINP)
  sim = q16sum(sim);
  sim = pl16comb(sim);
  sim = pl32comb(sim);
  if (lane == 0) out[i * BT + c] = sim;
}

extern "C" void kernel_launch(void* const* d_in, const int* in_sizes, int n_in,
                              void* d_out, int out_size, void* d_ws, size_t ws_size,
                              hipStream_t stream){
  const float* imgs = (const float*)d_in[0];
  const float* caps = (const float*)d_in[1];
  const int* il = (const int*)d_in[2];
  const int* cl = (const int*)d_in[3];
  float* out = (float*)d_out;

  unsigned short* Ab = (unsigned short*)d_ws;               // [4608][1024] bf16
  unsigned short* Bb = Ab + (size_t)BI * RR * DD;           // [6400][1024] bf16
  float* fg = (float*)(Bb + (size_t)BT * WW * DD);          // [4608][6400] f32
  int* rowoff = (int*)(fg + (size_t)BI * RR * NN);          // [129]
  int* coloff = rowoff + 129;                               // [129]

  prefix_kernel<<<1, 256, 0, stream>>>(il, cl, rowoff, coloff);
  gather_cvt_kernel<<<BI * RR + BT * WW, 256, 0, stream>>>(
      imgs, caps, il, cl, rowoff, coloff, Ab, Bb);
  gemm_kernel<<<36 * 50, 256, 0, stream>>>(Ab, Bb, rowoff, coloff, fg);
  sink_kernel<<<(BI * BT) / 4, 256, 0, stream>>>(fg, il, cl, rowoff, coloff, out);
}

// Round 10
// 115.264 us; speedup vs baseline: 1.3283x; 1.0102x over previous
//
#include <hip/hip_runtime.h>
#include <stdint.h>

#define BI 128
#define BT 128
#define RR 36
#define WW 50
#define DD 1024
#define NN 6400       /* fg row stride, static */
#define SEPS 1e-6f
#define L2E20 28.853900817779268f   /* 20/ln2 */

typedef __attribute__((ext_vector_type(8))) short short8v;
typedef __attribute__((ext_vector_type(4))) float float4v;
typedef __attribute__((ext_vector_type(2))) unsigned int uint2v;

__device__ __forceinline__ unsigned short f2bf(float f){
  unsigned u = __float_as_uint(f);
  return (unsigned short)((u + 0x7FFFu + ((u >> 16) & 1u)) >> 16);
}

// ---- exclusive prefix scan of il (128) and cl (128); dst[128] = total ----
__global__ __launch_bounds__(256) void prefix_kernel(
    const int* __restrict__ il, const int* __restrict__ cl,
    int* __restrict__ rowoff, int* __restrict__ coloff){
  __shared__ int buf[2][128];
  const int t = threadIdx.x;
  const int which = t >> 7, j = t & 127;
  const int v = which ? cl[j] : il[j];
  buf[which][j] = v;
  __syncthreads();
  #pragma unroll
  for (int off = 1; off < 128; off <<= 1){
    int x = (j >= off) ? buf[which][j - off] : 0;
    __syncthreads();
    buf[which][j] += x;
    __syncthreads();
  }
  int* dst = which ? coloff : rowoff;
  dst[j] = buf[which][j] - v;                 // exclusive
  if (j == 127) dst[128] = buf[which][127];   // total (M' / N')
}

// ---- gather valid rows + f32->bf16 convert. Block = one source row. ----
__global__ __launch_bounds__(256) void gather_cvt_kernel(
    const float* __restrict__ imgs, const float* __restrict__ caps,
    const int* __restrict__ il, const int* __restrict__ cl,
    const int* __restrict__ rowoff, const int* __restrict__ coloff,
    unsigned short* __restrict__ Ab, unsigned short* __restrict__ Bb){
  const int b = blockIdx.x;
  const int t = threadIdx.x;
  if (b < BI * RR){
    const int i = b / RR, r = b % RR;
    if (r >= il[i]) return;
    const float4 v = *(const float4*)(imgs + (size_t)b * DD + t * 4);
    ushort4 o = make_ushort4(f2bf(v.x), f2bf(v.y), f2bf(v.z), f2bf(v.w));
    *(ushort4*)(Ab + (size_t)(rowoff[i] + r) * DD + t * 4) = o;
  } else {
    const int bb = b - BI * RR;
    const int c = bb / WW, w = bb % WW;
    if (w >= cl[c]) return;
    const float4 v = *(const float4*)(caps + (size_t)bb * DD + t * 4);
    ushort4 o = make_ushort4(f2bf(v.x), f2bf(v.y), f2bf(v.z), f2bf(v.w));
    *(ushort4*)(Bb + (size_t)(coloff[c] + w) * DD + t * 4) = o;
  }
}

// ---- 128x128 GEMM, BK=32, TRIPLE-buffered LDS (3 x 16KB = 48KB), depth-2
// prefetch: stage chunk c+2 while computing c; steady-state vmcnt(8) (2
// stages x 4 loads in flight, never drained mid-loop). 10x3 unrolled chunk
// loop keeps buffer indices static. Row-pair bank swizzle as R9 (validated). ----
__global__ __launch_bounds__(256) void gemm_kernel(
    const unsigned short* __restrict__ A, const unsigned short* __restrict__ B,
    const int* __restrict__ rowoff, const int* __restrict__ coloff,
    float* __restrict__ C){
  __shared__ __align__(16) unsigned char LDS[49152];
  const int bx = blockIdx.x;
  const int swz = (bx & 7) * 225 + (bx >> 3);     // 1800 = 8*225, bijective
  const int mb = swz / 50, nb = swz % 50;
  const int m0 = mb * 128, n0 = nb * 128;
  const int Mp = rowoff[BI];                      // M' (runtime)
  const int Np = coloff[BT];                      // N'
  if (m0 >= Mp || n0 >= Np) return;               // uniform early-exit

  const int tid = threadIdx.x;
  const int lane = tid & 63, wv = tid >> 6;
  const int l15 = lane & 15, lhi = lane >> 4;
  const int wr = wv >> 1, wc = wv & 1;            // 2x2 wave grid, 64x64/wave

  // staging sources: 4 units/thread/chunk (u = j*256+tid; A: u<512, B: u>=512)
  const unsigned short* sp[4];
  #pragma unroll
  for (int j = 0; j < 4; j++){
    const int u = j * 256 + tid;
    const int v = u & 511;
    const int sup = v >> 3, slot = v & 7;
    const int sub = slot ^ (sup & 7);             // inverse of store swizzle
    const int row = sup * 2 + (sub >> 2);
    const int kg  = sub & 3;
    sp[j] = ((u < 512) ? (A + (size_t)(m0 + row) * DD)
                       : (B + (size_t)(n0 + row) * DD)) + kg * 8;
  }

  float4v acc[4][4];
  #pragma unroll
  for (int a1 = 0; a1 < 4; a1++)
    #pragma unroll
    for (int b1 = 0; b1 < 4; b1++)
      acc[a1][b1] = (float4v){0.f, 0.f, 0.f, 0.f};

#define STAGE(BUF, CH) { \
    _Pragma("unroll") \
    for (int j = 0; j < 4; j++) \
      __builtin_amdgcn_global_load_lds( \
          (const __attribute__((address_space(1))) void*)(sp[j] + (CH) * 32), \
          (__attribute__((address_space(3))) void*)(LDS + (BUF) * 16384 + (j * 256 + tid) * 16), \
          16, 0, 0); }

#define LUNIT(row) (((row) >> 1) * 8 + (((((row) & 1) << 2) + lhi) ^ (((row) >> 1) & 7)))

#define COMPUTE(BUF) { \
    short8v af[4], bf[4]; \
    _Pragma("unroll") \
    for (int tr = 0; tr < 4; tr++){ \
      const int row = wr * 64 + tr * 16 + l15; \
      af[tr] = *(const short8v*)(LDS + (BUF) * 16384 + LUNIT(row) * 16); \
    } \
    _Pragma("unroll") \
    for (int tw = 0; tw < 4; tw++){ \
      const int row = wc * 64 + tw * 16 + l15; \
      bf[tw] = *(const short8v*)(LDS + (BUF) * 16384 + 8192 + LUNIT(row) * 16); \
    } \
    _Pragma("unroll") \
    for (int tr = 0; tr < 4; tr++) \
      _Pragma("unroll") \
      for (int tw = 0; tw < 4; tw++) \
        acc[tr][tw] = __builtin_amdgcn_mfma_f32_16x16x32_bf16( \
            af[tr], bf[tw], acc[tr][tw], 0, 0, 0); }

#define WAIT8  asm volatile("s_waitcnt vmcnt(8)" ::: "memory")
#define WAIT4  asm volatile("s_waitcnt vmcnt(4)" ::: "memory")
#define WAIT0  asm volatile("s_waitcnt vmcnt(0)" ::: "memory")
#define BAR    __builtin_amdgcn_s_barrier()

  STAGE(0, 0);                    // prologue: chunks 0,1 in flight
  STAGE(1, 1);
  #pragma unroll 1
  for (int k = 0; k < 10; k++){   // chunks 3k, 3k+1, 3k+2 in bufs 0,1,2
    const int c = 3 * k;
    STAGE(2, c + 2); WAIT8; BAR; COMPUTE(0); BAR;   // compute chunk c
    STAGE(0, c + 3); WAIT8; BAR; COMPUTE(1); BAR;   // chunk c+1
    STAGE(1, c + 4); WAIT8; BAR; COMPUTE(2); BAR;   // chunk c+2
  }
  WAIT4; BAR; COMPUTE(0); BAR;    // chunk 30 (staged at k=9 step B)
  WAIT0; BAR; COMPUTE(1);         // chunk 31 (staged at k=9 step C)

#undef STAGE
#undef LUNIT
#undef COMPUTE
#undef WAIT8
#undef WAIT4
#undef WAIT0
#undef BAR

  // C/D layout: col = lane&15, row = lhi*4 + j (m89/m91, validated R1-R9)
  #pragma unroll
  for (int tr = 0; tr < 4; tr++)
    #pragma unroll
    for (int tw = 0; tw < 4; tw++)
      #pragma unroll
      for (int j = 0; j < 4; j++){
        int m = m0 + wr * 64 + tr * 16 + lhi * 4 + j;
        int n = n0 + wc * 64 + tw * 16 + l15;
        C[(size_t)m * NN + n] = acc[tr][tw][j];
      }
}

// ---- reduction helpers (validated R1-R9) ----
template<int CTRL>
__device__ __forceinline__ float dpp_add(float x){
  int y = __builtin_amdgcn_mov_dpp(__float_as_int(x), CTRL, 0xF, 0xF, true);
  return x + __int_as_float(y);
}
__device__ __forceinline__ float q16sum(float x){
  x = dpp_add<0x121>(x);   // row_ror:1
  x = dpp_add<0x122>(x);   // row_ror:2
  x = dpp_add<0x124>(x);   // row_ror:4
  x = dpp_add<0x128>(x);   // row_ror:8
  return x;
}
__device__ __forceinline__ float pl16comb(float x){
  unsigned xi = __float_as_uint(x);
  uint2v r = __builtin_amdgcn_permlane16_swap(xi, xi, false, false);
  return __uint_as_float(r[0]) + __uint_as_float(r[1]);
}
__device__ __forceinline__ float pl32comb(float x){
  unsigned xi = __float_as_uint(x);
  uint2v r = __builtin_amdgcn_permlane32_swap(xi, xi, false, false);
  return __uint_as_float(r[0]) + __uint_as_float(r[1]);
}

// ---- Sinkhorn: ONE pair per wave, 4-way row-split (validated R8/R9). ----
#define RL9(X) X(0) X(1) X(2) X(3) X(4) X(5) X(6) X(7) X(8)
#define DECLP(k) float p##k##0=0.f, p##k##1=0.f, p##k##2=0.f, p##k##3=0.f;
#define INITP(k) { \
    const int vo = off0 + k * NN; \
    const bool rv = (r0 + k) < ilen; \
    const float a0 = base[vo], a1 = base[vo + 16]; \
    const float a2 = base[vo + 32], a3 = base[vo + 48]; \
    p##k##0 = (rv && v0) ? exp2f(fmaf(a0, L2E20, -L2E20)) : 0.f; \
    p##k##1 = (rv && v1) ? exp2f(fmaf(a1, L2E20, -L2E20)) : 0.f; \
    p##k##2 = (rv && v2) ? exp2f(fmaf(a2, L2E20, -L2E20)) : 0.f; \
    p##k##3 = (rv && v3) ? exp2f(fmaf(a3, L2E20, -L2E20)) : 0.f; \
    ts += (p##k##0 + p##k##1) + (p##k##2 + p##k##3); }
#define SCAL0(k) { p##k##0 *= sc; p##k##1 *= sc; p##k##2 *= sc; p##k##3 *= sc; }
#define ROWP(k) { \
    float u = (p##k##0 + p##k##1) + (p##k##2 + p##k##3); \
    u = q16sum(u); \
    const float rs = __fdividef(inv_il, u + SEPS); \
    p##k##0 *= rs; p##k##1 *= rs; p##k##2 *= rs; p##k##3 *= rs; }
#define COLA(k) { s0 += p##k##0; s1 += p##k##1; s2 += p##k##2; s3 += p##k##3; }
#define CSC(k) { p##k##0 *= cs0; p##k##1 *= cs1; p##k##2 *= cs2; p##k##3 *= cs3; }
#define FINP(k) { \
    const int vo = off0 + k * NN; \
    sim = fmaf(base[vo],      p##k##0, sim); \
    sim = fmaf(base[vo + 16], p##k##1, sim); \
    sim = fmaf(base[vo + 32], p##k##2, sim); \
    sim = fmaf(base[vo + 48], p##k##3, sim); }

__global__ __launch_bounds__(256) void sink_kernel(
    const float* __restrict__ fg, const int* __restrict__ il,
    const int* __restrict__ cl, const int* __restrict__ rowoff,
    const int* __restrict__ coloff, float* __restrict__ out){
  const int lane = threadIdx.x & 63;
  const int gw = blockIdx.x * 4 + (threadIdx.x >> 6);   // 16384 waves
  const int i = gw >> 7, c = gw & 127;
  const int q = lane >> 4, t = lane & 15;

  const int ilen = __builtin_amdgcn_readfirstlane(il[i]);
  const int clen = __builtin_amdgcn_readfirstlane(cl[c]);
  const int ro   = __builtin_amdgcn_readfirstlane(rowoff[i]);
  const int co   = __builtin_amdgcn_readfirstlane(coloff[c]);
  const float* base = fg + (size_t)ro * NN + co;        // wave-uniform (saddr)
  const float inv_il = __fdividef(1.0f, (float)ilen);
  const float inv_cl = __fdividef(1.0f, (float)clen);
  const bool v0 = (t      < clen);
  const bool v1 = (t + 16 < clen);
  const bool v2 = (t + 32 < clen);
  const bool v3 = (t + 48 < clen);
  const int r0 = 9 * q;                                 // this quarter's rows
  const int off0 = r0 * NN + t;                         // 32-bit elem offset

  RL9(DECLP)

  float ts = 0.f;
  RL9(INITP)
  ts = q16sum(ts);
  ts = pl16comb(ts);
  ts = pl32comb(ts);
  const float sc = __fdividef(1.0f, ts + SEPS);         // P /= (sum + EPS)
  RL9(SCAL0)

  for (int it = 0; it < 3; it++){
    RL9(ROWP)                                           // 9 rounds, 4 rows each
    float s0 = 0.f, s1 = 0.f, s2 = 0.f, s3 = 0.f;
    RL9(COLA)
    s0 = pl16comb(s0); s0 = pl32comb(s0);
    s1 = pl16comb(s1); s1 = pl32comb(s1);
    s2 = pl16comb(s2); s2 = pl32comb(s2);
    s3 = pl16comb(s3); s3 = pl32comb(s3);
    const float cs0 = __fdividef(inv_cl, s0 + SEPS);
    const float cs1 = __fdividef(inv_cl, s1 + SEPS);
    const float cs2 = __fdividef(inv_cl, s2 + SEPS);
    const float cs3 = __fdividef(inv_cl, s3 + SEPS);
    RL9(CSC)
  }

  float sim = 0.f;
  RL9(FINP)
  sim = q16sum(sim);
  sim = pl16comb(sim);
  sim = pl32comb(sim);
  if (lane == 0) out[i * BT + c] = sim;
}

extern "C" void kernel_launch(void* const* d_in, const int* in_sizes, int n_in,
                              void* d_out, int out_size, void* d_ws, size_t ws_size,
                              hipStream_t stream){
  const float* imgs = (const float*)d_in[0];
  const float* caps = (const float*)d_in[1];
  const int* il = (const int*)d_in[2];
  const int* cl = (const int*)d_in[3];
  float* out = (float*)d_out;

  unsigned short* Ab = (unsigned short*)d_ws;               // [4608][1024] bf16
  unsigned short* Bb = Ab + (size_t)BI * RR * DD;           // [6400][1024] bf16
  float* fg = (float*)(Bb + (size_t)BT * WW * DD);          // [4608][6400] f32
  int* rowoff = (int*)(fg + (size_t)BI * RR * NN);          // [129]
  int* coloff = rowoff + 129;                               // [129]

  prefix_kernel<<<1, 256, 0, stream>>>(il, cl, rowoff, coloff);
  gather_cvt_kernel<<<BI * RR + BT * WW, 256, 0, stream>>>(
      imgs, caps, il, cl, rowoff, coloff, Ab, Bb);
  gemm_kernel<<<36 * 50, 256, 0, stream>>>(Ab, Bb, rowoff, coloff, fg);
  sink_kernel<<<(BI * BT) / 4, 256, 0, stream>>>(fg, il, cl, rowoff, coloff, out);
}

// Round 11
// 108.145 us; speedup vs baseline: 1.4157x; 1.0658x over previous
//
#include <hip/hip_runtime.h>
#include <stdint.h>

#define BI 128
#define BT 128
#define RR 36
#define WW 50
#define DD 1024
#define NN 6400       /* fg row stride, static */
#define SEPS 1e-6f
#define L2E20 28.853900817779268f   /* 20/ln2 */

typedef __attribute__((ext_vector_type(8))) short short8v;
typedef __attribute__((ext_vector_type(4))) float float4v;
typedef __attribute__((ext_vector_type(2))) unsigned int uint2v;

__device__ __forceinline__ unsigned short f2bf(float f){
  unsigned u = __float_as_uint(f);
  return (unsigned short)((u + 0x7FFFu + ((u >> 16) & 1u)) >> 16);
}

// ---- exclusive prefix scan of il (128) and cl (128); dst[128] = total ----
__global__ __launch_bounds__(256) void prefix_kernel(
    const int* __restrict__ il, const int* __restrict__ cl,
    int* __restrict__ rowoff, int* __restrict__ coloff){
  __shared__ int buf[2][128];
  const int t = threadIdx.x;
  const int which = t >> 7, j = t & 127;
  const int v = which ? cl[j] : il[j];
  buf[which][j] = v;
  __syncthreads();
  #pragma unroll
  for (int off = 1; off < 128; off <<= 1){
    int x = (j >= off) ? buf[which][j - off] : 0;
    __syncthreads();
    buf[which][j] += x;
    __syncthreads();
  }
  int* dst = which ? coloff : rowoff;
  dst[j] = buf[which][j] - v;                 // exclusive
  if (j == 127) dst[128] = buf[which][127];   // total (M' / N')
}

// ---- gather valid rows + f32->bf16 convert. Block = one source row. ----
__global__ __launch_bounds__(256) void gather_cvt_kernel(
    const float* __restrict__ imgs, const float* __restrict__ caps,
    const int* __restrict__ il, const int* __restrict__ cl,
    const int* __restrict__ rowoff, const int* __restrict__ coloff,
    unsigned short* __restrict__ Ab, unsigned short* __restrict__ Bb){
  const int b = blockIdx.x;
  const int t = threadIdx.x;
  if (b < BI * RR){
    const int i = b / RR, r = b % RR;
    if (r >= il[i]) return;
    const float4 v = *(const float4*)(imgs + (size_t)b * DD + t * 4);
    ushort4 o = make_ushort4(f2bf(v.x), f2bf(v.y), f2bf(v.z), f2bf(v.w));
    *(ushort4*)(Ab + (size_t)(rowoff[i] + r) * DD + t * 4) = o;
  } else {
    const int bb = b - BI * RR;
    const int c = bb / WW, w = bb % WW;
    if (w >= cl[c]) return;
    const float4 v = *(const float4*)(caps + (size_t)bb * DD + t * 4);
    ushort4 o = make_ushort4(f2bf(v.x), f2bf(v.y), f2bf(v.z), f2bf(v.w));
    *(ushort4*)(Bb + (size_t)(coloff[c] + w) * DD + t * 4) = o;
  }
}

// ---- 128x128 GEMM, BK=32, triple-buffered LDS, depth-2 prefetch (R10).
// R11: (1) runtime-COMPACT grid — active tiles occupy bx in [0, nmb*nnb),
// so hardware round-robin spreads them over ALL 8 XCDs (the static swizzle
// previously parked XCDs 6-7 on instantly-exiting blocks); (2) non-temporal
// C-writes keep the 44MB fg stream from evicting A/B panels out of L2/L3
// (R10 FETCH was 77MB vs 13MB unique input). ----
__global__ __launch_bounds__(256) void gemm_kernel(
    const unsigned short* __restrict__ A, const unsigned short* __restrict__ B,
    const int* __restrict__ rowoff, const int* __restrict__ coloff,
    float* __restrict__ C){
  __shared__ __align__(16) unsigned char LDS[49152];
  const int Mp = rowoff[BI];                      // M' (runtime)
  const int Np = coloff[BT];                      // N'
  const int nnb = (Np + 127) >> 7;
  const int nact = ((Mp + 127) >> 7) * nnb;
  const int bx = blockIdx.x;
  if (bx >= nact) return;                         // compact early-exit
  const int mb = bx / nnb, nb = bx - mb * nnb;
  const int m0 = mb * 128, n0 = nb * 128;

  const int tid = threadIdx.x;
  const int lane = tid & 63, wv = tid >> 6;
  const int l15 = lane & 15, lhi = lane >> 4;
  const int wr = wv >> 1, wc = wv & 1;            // 2x2 wave grid, 64x64/wave

  // staging sources: 4 units/thread/chunk (u = j*256+tid; A: u<512, B: u>=512)
  const unsigned short* sp[4];
  #pragma unroll
  for (int j = 0; j < 4; j++){
    const int u = j * 256 + tid;
    const int v = u & 511;
    const int sup = v >> 3, slot = v & 7;
    const int sub = slot ^ (sup & 7);             // inverse of store swizzle
    const int row = sup * 2 + (sub >> 2);
    const int kg  = sub & 3;
    sp[j] = ((u < 512) ? (A + (size_t)(m0 + row) * DD)
                       : (B + (size_t)(n0 + row) * DD)) + kg * 8;
  }

  float4v acc[4][4];
  #pragma unroll
  for (int a1 = 0; a1 < 4; a1++)
    #pragma unroll
    for (int b1 = 0; b1 < 4; b1++)
      acc[a1][b1] = (float4v){0.f, 0.f, 0.f, 0.f};

#define STAGE(BUF, CH) { \
    _Pragma("unroll") \
    for (int j = 0; j < 4; j++) \
      __builtin_amdgcn_global_load_lds( \
          (const __attribute__((address_space(1))) void*)(sp[j] + (CH) * 32), \
          (__attribute__((address_space(3))) void*)(LDS + (BUF) * 16384 + (j * 256 + tid) * 16), \
          16, 0, 0); }

#define LUNIT(row) (((row) >> 1) * 8 + (((((row) & 1) << 2) + lhi) ^ (((row) >> 1) & 7)))

#define COMPUTE(BUF) { \
    short8v af[4], bf[4]; \
    _Pragma("unroll") \
    for (int tr = 0; tr < 4; tr++){ \
      const int row = wr * 64 + tr * 16 + l15; \
      af[tr] = *(const short8v*)(LDS + (BUF) * 16384 + LUNIT(row) * 16); \
    } \
    _Pragma("unroll") \
    for (int tw = 0; tw < 4; tw++){ \
      const int row = wc * 64 + tw * 16 + l15; \
      bf[tw] = *(const short8v*)(LDS + (BUF) * 16384 + 8192 + LUNIT(row) * 16); \
    } \
    _Pragma("unroll") \
    for (int tr = 0; tr < 4; tr++) \
      _Pragma("unroll") \
      for (int tw = 0; tw < 4; tw++) \
        acc[tr][tw] = __builtin_amdgcn_mfma_f32_16x16x32_bf16( \
            af[tr], bf[tw], acc[tr][tw], 0, 0, 0); }

#define WAIT8  asm volatile("s_waitcnt vmcnt(8)" ::: "memory")
#define WAIT4  asm volatile("s_waitcnt vmcnt(4)" ::: "memory")
#define WAIT0  asm volatile("s_waitcnt vmcnt(0)" ::: "memory")
#define BAR    __builtin_amdgcn_s_barrier()

  STAGE(0, 0);                    // prologue: chunks 0,1 in flight
  STAGE(1, 1);
  #pragma unroll 1
  for (int k = 0; k < 10; k++){   // chunks 3k, 3k+1, 3k+2 in bufs 0,1,2
    const int c = 3 * k;
    STAGE(2, c + 2); WAIT8; BAR; COMPUTE(0); BAR;   // compute chunk c
    STAGE(0, c + 3); WAIT8; BAR; COMPUTE(1); BAR;   // chunk c+1
    STAGE(1, c + 4); WAIT8; BAR; COMPUTE(2); BAR;   // chunk c+2
  }
  WAIT4; BAR; COMPUTE(0); BAR;    // chunk 30 (staged at k=9 step B)
  WAIT0; BAR; COMPUTE(1);         // chunk 31 (staged at k=9 step C)

#undef STAGE
#undef LUNIT
#undef COMPUTE
#undef WAIT8
#undef WAIT4
#undef WAIT0
#undef BAR

  // C/D layout: col = lane&15, row = lhi*4 + j (m89/m91, validated R1-R10).
  // Non-temporal: fg is consumed once, much later, by sink — don't cache it.
  #pragma unroll
  for (int tr = 0; tr < 4; tr++)
    #pragma unroll
    for (int tw = 0; tw < 4; tw++)
      #pragma unroll
      for (int j = 0; j < 4; j++){
        int m = m0 + wr * 64 + tr * 16 + lhi * 4 + j;
        int n = n0 + wc * 64 + tw * 16 + l15;
        __builtin_nontemporal_store(acc[tr][tw][j], &C[(size_t)m * NN + n]);
      }
}

// ---- reduction helpers (validated R1-R10) ----
template<int CTRL>
__device__ __forceinline__ float dpp_add(float x){
  int y = __builtin_amdgcn_mov_dpp(__float_as_int(x), CTRL, 0xF, 0xF, true);
  return x + __int_as_float(y);
}
__device__ __forceinline__ float q16sum(float x){
  x = dpp_add<0x121>(x);   // row_ror:1
  x = dpp_add<0x122>(x);   // row_ror:2
  x = dpp_add<0x124>(x);   // row_ror:4
  x = dpp_add<0x128>(x);   // row_ror:8
  return x;
}
__device__ __forceinline__ float pl16comb(float x){
  unsigned xi = __float_as_uint(x);
  uint2v r = __builtin_amdgcn_permlane16_swap(xi, xi, false, false);
  return __uint_as_float(r[0]) + __uint_as_float(r[1]);
}
__device__ __forceinline__ float pl32comb(float x){
  unsigned xi = __float_as_uint(x);
  uint2v r = __builtin_amdgcn_permlane32_swap(xi, xi, false, false);
  return __uint_as_float(r[0]) + __uint_as_float(r[1]);
}

// ---- Sinkhorn: ONE pair per wave, 4-way row-split (validated R8-R10). ----
#define RL9(X) X(0) X(1) X(2) X(3) X(4) X(5) X(6) X(7) X(8)
#define DECLP(k) float p##k##0=0.f, p##k##1=0.f, p##k##2=0.f, p##k##3=0.f;
#define INITP(k) { \
    const int vo = off0 + k * NN; \
    const bool rv = (r0 + k) < ilen; \
    const float a0 = base[vo], a1 = base[vo + 16]; \
    const float a2 = base[vo + 32], a3 = base[vo + 48]; \
    p##k##0 = (rv && v0) ? exp2f(fmaf(a0, L2E20, -L2E20)) : 0.f; \
    p##k##1 = (rv && v1) ? exp2f(fmaf(a1, L2E20, -L2E20)) : 0.f; \
    p##k##2 = (rv && v2) ? exp2f(fmaf(a2, L2E20, -L2E20)) : 0.f; \
    p##k##3 = (rv && v3) ? exp2f(fmaf(a3, L2E20, -L2E20)) : 0.f; \
    ts += (p##k##0 + p##k##1) + (p##k##2 + p##k##3); }
#define SCAL0(k) { p##k##0 *= sc; p##k##1 *= sc; p##k##2 *= sc; p##k##3 *= sc; }
#define ROWP(k) { \
    float u = (p##k##0 + p##k##1) + (p##k##2 + p##k##3); \
    u = q16sum(u); \
    const float rs = __fdividef(inv_il, u + SEPS); \
    p##k##0 *= rs; p##k##1 *= rs; p##k##2 *= rs; p##k##3 *= rs; }
#define COLA(k) { s0 += p##k##0; s1 += p##k##1; s2 += p##k##2; s3 += p##k##3; }
#define CSC(k) { p##k##0 *= cs0; p##k##1 *= cs1; p##k##2 *= cs2; p##k##3 *= cs3; }
#define FINP(k) { \
    const int vo = off0 + k * NN; \
    sim = fmaf(base[vo],      p##k##0, sim); \
    sim = fmaf(base[vo + 16], p##k##1, sim); \
    sim = fmaf(base[vo + 32], p##k##2, sim); \
    sim = fmaf(base[vo + 48], p##k##3, sim); }

__global__ __launch_bounds__(256) void sink_kernel(
    const float* __restrict__ fg, const int* __restrict__ il,
    const int* __restrict__ cl, const int* __restrict__ rowoff,
    const int* __restrict__ coloff, float* __restrict__ out){
  const int lane = threadIdx.x & 63;
  const int gw = blockIdx.x * 4 + (threadIdx.x >> 6);   // 16384 waves
  const int i = gw >> 7, c = gw & 127;
  const int q = lane >> 4, t = lane & 15;

  const int ilen = __builtin_amdgcn_readfirstlane(il[i]);
  const int clen = __builtin_amdgcn_readfirstlane(cl[c]);
  const int ro   = __builtin_amdgcn_readfirstlane(rowoff[i]);
  const int co   = __builtin_amdgcn_readfirstlane(coloff[c]);
  const float* base = fg + (size_t)ro * NN + co;        // wave-uniform (saddr)
  const float inv_il = __fdividef(1.0f, (float)ilen);
  const float inv_cl = __fdividef(1.0f, (float)clen);
  const bool v0 = (t      < clen);
  const bool v1 = (t + 16 < clen);
  const bool v2 = (t + 32 < clen);
  const bool v3 = (t + 48 < clen);
  const int r0 = 9 * q;                                 // this quarter's rows
  const int off0 = r0 * NN + t;                         // 32-bit elem offset

  RL9(DECLP)

  float ts = 0.f;
  RL9(INITP)
  ts = q16sum(ts);
  ts = pl16comb(ts);
  ts = pl32comb(ts);
  const float sc = __fdividef(1.0f, ts + SEPS);         // P /= (sum + EPS)
  RL9(SCAL0)

  for (int it = 0; it < 3; it++){
    RL9(ROWP)                                           // 9 rounds, 4 rows each
    float s0 = 0.f, s1 = 0.f, s2 = 0.f, s3 = 0.f;
    RL9(COLA)
    s0 = pl16comb(s0); s0 = pl32comb(s0);
    s1 = pl16comb(s1); s1 = pl32comb(s1);
    s2 = pl16comb(s2); s2 = pl32comb(s2);
    s3 = pl16comb(s3); s3 = pl32comb(s3);
    const float cs0 = __fdividef(inv_cl, s0 + SEPS);
    const float cs1 = __fdividef(inv_cl, s1 + SEPS);
    const float cs2 = __fdividef(inv_cl, s2 + SEPS);
    const float cs3 = __fdividef(inv_cl, s3 + SEPS);
    RL9(CSC)
  }

  float sim = 0.f;
  RL9(FINP)
  sim = q16sum(sim);
  sim = pl16comb(sim);
  sim = pl32comb(sim);
  if (lane == 0) out[i * BT + c] = sim;
}

extern "C" void kernel_launch(void* const* d_in, const int* in_sizes, int n_in,
                              void* d_out, int out_size, void* d_ws, size_t ws_size,
                              hipStream_t stream){
  const float* imgs = (const float*)d_in[0];
  const float* caps = (const float*)d_in[1];
  const int* il = (const int*)d_in[2];
  const int* cl = (const int*)d_in[3];
  float* out = (float*)d_out;

  unsigned short* Ab = (unsigned short*)d_ws;               // [4608][1024] bf16
  unsigned short* Bb = Ab + (size_t)BI * RR * DD;           // [6400][1024] bf16
  float* fg = (float*)(Bb + (size_t)BT * WW * DD);          // [4608][6400] f32
  int* rowoff = (int*)(fg + (size_t)BI * RR * NN);          // [129]
  int* coloff = rowoff + 129;                               // [129]

  prefix_kernel<<<1, 256, 0, stream>>>(il, cl, rowoff, coloff);
  gather_cvt_kernel<<<BI * RR + BT * WW, 256, 0, stream>>>(
      imgs, caps, il, cl, rowoff, coloff, Ab, Bb);
  gemm_kernel<<<36 * 50, 256, 0, stream>>>(Ab, Bb, rowoff, coloff, fg);
  sink_kernel<<<(BI * BT) / 4, 256, 0, stream>>>(fg, il, cl, rowoff, coloff, out);
}